// Round 5
// baseline (476.912 us; speedup 1.0000x reference)
//
#include <hip/hip_runtime.h>
#include <math.h>

#define R_ 4
#define B_ 16
#define HQ_ 32
#define HKV_ 2
#define G_ 16
#define D_ 128
#define S_ 32     // reference split count (semantically observable via m_r!)
#define CT_ 32    // tokens per sub-chunk task (half-split)
#define L_ 2048
#define P_ 32768
#define KSTR 136  // halves per q_s row: 272B, 16B-aligned rows
#define PSTR 20   // floats per p_s row: 80B stride -> 16B-aligned float4 reads
#define NEGINF (-INFINITY)

typedef _Float16 h4 __attribute__((ext_vector_type(4)));
typedef _Float16 h8 __attribute__((ext_vector_type(8)));
typedef float    fx4 __attribute__((ext_vector_type(4)));

// ws layout (task = (rb,hkv,s,c), widx = ((rb*HKV+hkv)*S + s)*2 + c, 8192 tasks):
//   pm_ws [8192][G] float   (task max score; -inf if empty)
//   se_ws [8192][G] float   (sum exp(s - pm); 0 if empty)
//   chunk_acc [8192][G][D] half  (sum exp(s - pm) * v; UNWRITTEN if empty)
//
// Reference semantics note: m_r = max over the S=32 reference splits of the
// per-split LSE (per = ceil(len/32)). This is observable in the output (the
// combine weights acc_r = exp(lse_r - m_r)*o_norm by exp(lse_r - M) without
// renormalizing), so stage2 reconstructs lse_s per reference split exactly
// from the two half-split partials. Uniform-chunk m_r (round 4) FAILS.

__global__ __launch_bounds__(128, 6) void fd_stage1(
    const float* __restrict__ q, const float* __restrict__ kc,
    const float* __restrict__ vc, const int* __restrict__ bt,
    const int* __restrict__ lens,
    float* __restrict__ pm_ws, float* __restrict__ se_ws,
    _Float16* __restrict__ chunk_acc)
{
  const int t   = threadIdx.x;
  const int blk = blockIdx.x;            // grid = 2*S_*64*HKV_ = 8192, c-major
  const int c   = blk >> 12;             // 0 first (large halves), then 1
  const int s   = (blk >> 7) & 31;
  const int rb  = (blk >> 1) & 63;
  const int hkv = blk & 1;
  const int r   = rb >> 4, b = rb & 15;

  const int len = lens[rb];
  const int per = (len + 31) >> 5;       // ceil(len/32), 2..64
  const int sn0 = s*per;                 // reference split start
  const int stn = min(per, len - sn0);   // split token count (may be <=0)
  const int n0  = sn0 + c*CT_;           // sub-chunk start
  const int tn  = min(stn - c*CT_, CT_); // sub-chunk tokens, block-uniform

  const int widx = ((rb*HKV_ + hkv)*S_ + s)*2 + c;
  float* pm_out = pm_ws + widx*G_;
  float* se_out = se_ws + widx*G_;
  _Float16* ca  = chunk_acc + (size_t)widx*(G_*D_);

  if (tn <= 0) {                         // empty task: marker only, no acc write
    if (t < G_) { pm_out[t] = NEGINF; se_out[t] = 0.f; }
    return;
  }

  __shared__ _Float16 q_s[G_][KSTR];                  // 4352 B
  __shared__ __align__(16) float p_s[CT_][PSTR];      // 2560 B
  __shared__ int      pg_s[CT_];                      // 128 B
  __shared__ float2   red_s[2][G_];                   // 256 B  (~7.3 KB total)

  const int* btb = bt + rb*L_;
  const float* kvk = kc + (size_t)r*(P_*HKV_*D_) + hkv*D_;
  const float* kvv = vc + (size_t)r*(P_*HKV_*D_) + hkv*D_;

  // page table slice: n0 <= 31*64 + 32 = 2016, n0+31 <= 2047, always in-bounds
  if (t < CT_) pg_s[t] = btb[n0 + t];

  // stage Q (fp32 -> fp16): 16 heads x 128, coalesced
  {
    const float* qb = q + (b*HQ_ + hkv*G_)*D_;
    int fi = t;
    #pragma unroll
    for (int i = 0; i < 4; ++i, fi += 128) {
      const int g = fi >> 5, dd = (fi & 31)*4;
      const float4 v = *(const float4*)&qb[g*D_ + dd];
      h4 hv; hv.x=(_Float16)v.x; hv.y=(_Float16)v.y; hv.z=(_Float16)v.z; hv.w=(_Float16)v.w;
      *(h4*)&q_s[g][dd] = hv;
    }
  }
  __syncthreads();

  // ---- scores via MFMA, K straight from global.
  // Wave w (0..1) computes D[token 16w..16w+15][head 0..15].
  // A-row = K token row (lane&15), k = 32c + 8*(lane>>4)+j; rows >= tn masked
  // at load (af=0; score later -inf'd). C/D: col(head)=lane&15,
  // row(token_local)=4*(lane>>4)+reg  [verified rounds 1-3].
  const int w  = t >> 6;                  // wave 0..1
  const int l  = t & 63;
  const int hh = l & 15;                  // head / A-row
  const int tq = l >> 4;                  // k-chunk selector
  const bool active = (16*w) < tn;        // wave-uniform

  fx4 d0 = {0.f,0.f,0.f,0.f};
  if (active) {
    const int row = 16*w + hh;
    const bool rowok = row < tn;
    const int pg = pg_s[row];             // valid address even when !rowok
    const float* kr = kvk + pg*(HKV_*D_) + 8*tq;
    #pragma unroll
    for (int cc = 0; cc < 4; ++cc) {      // K = 4 x 32 = 128
      h8 af = {};
      if (rowok) {
        const float4 f0 = *(const float4*)&kr[cc*32];
        const float4 f1 = *(const float4*)&kr[cc*32 + 4];
        af[0]=(_Float16)f0.x; af[1]=(_Float16)f0.y; af[2]=(_Float16)f0.z; af[3]=(_Float16)f0.w;
        af[4]=(_Float16)f1.x; af[5]=(_Float16)f1.y; af[6]=(_Float16)f1.z; af[7]=(_Float16)f1.w;
      }
      const h8 bf = *(const h8*)&q_s[hh][cc*32 + 8*tq];
      d0 = __builtin_amdgcn_mfma_f32_16x16x32_f16(af, bf, d0, 0, 0, 0);
    }
  }

  const float sc = 0.08838834764831845f;  // 128^-0.5
  const int nb = 16*w + 4*tq;             // this lane's token row base
  const float sv0 = (nb+0 < tn) ? d0[0]*sc : NEGINF;
  const float sv1 = (nb+1 < tn) ? d0[1]*sc : NEGINF;
  const float sv2 = (nb+2 < tn) ? d0[2]*sc : NEGINF;
  const float sv3 = (nb+3 < tn) ? d0[3]*sc : NEGINF;

  // wave-local per-head max over this wave's 16 tokens
  float pmw = fmaxf(fmaxf(sv0, sv1), fmaxf(sv2, sv3));
  pmw = fmaxf(pmw, __shfl_xor(pmw, 16));
  pmw = fmaxf(pmw, __shfl_xor(pmw, 32));
  const float pms = (pmw == NEGINF) ? 0.f : pmw;  // avoid (-inf)-(-inf)=NaN
  const float e0 = __expf(sv0 - pms);
  const float e1 = __expf(sv1 - pms);
  const float e2 = __expf(sv2 - pms);
  const float e3 = __expf(sv3 - pms);
  float psw = e0 + e1 + e2 + e3;
  psw += __shfl_xor(psw, 16);
  psw += __shfl_xor(psw, 32);

  if (l < 16) red_s[w][l] = make_float2(pmw, psw);
  __syncthreads();

  // cross-wave combine (2 waves): pm = task max, ps = sum exp(s - pm)
  const float2 r0 = red_s[0][hh], r1 = red_s[1][hh];
  const float pm = fmaxf(r0.x, r1.x);
  const float ps = r0.y*__expf(r0.x - pm) + r1.y*__expf(r1.x - pm);

  if (w == 0 && l < 16) {
    pm_out[l] = pm;                       // task max score
    se_out[l] = ps;                       // task sum exp(s - pm)
  }

  // p transposed: p_s[n][h] = exp(s - pm); rows >= tn of active wave write 0;
  // rows of inactive wave never read (PV loops n < tn)
  if (active) {
    const float cw = __expf(pmw - pm);    // pmw=-inf -> 0
    p_s[nb+0][hh] = e0*cw;
    p_s[nb+1][hh] = e1*cw;
    p_s[nb+2][hh] = e2*cw;
    p_s[nb+3][hh] = e3*cw;
  }
  __syncthreads();

  // PV: thread owns heads g4..g4+3 x dims d4..d4+3; V straight from global,
  // page index from LDS. Wave V-load = 512B contiguous per page row.
  const int d4 = (t & 31)*4;
  const int g4 = (t >> 5)*4;
  const float* vb = kvv + d4;
  float4 a0 = make_float4(0,0,0,0), a1 = make_float4(0,0,0,0);
  float4 a2 = make_float4(0,0,0,0), a3 = make_float4(0,0,0,0);
  #pragma unroll 4
  for (int n = 0; n < tn; ++n) {
    const int pg = pg_s[n];               // LDS broadcast
    const float4 v4 = *(const float4*)&vb[pg*(HKV_*D_)];
    const float4 pp = *(const float4*)&p_s[n][g4];   // 16B-aligned (PSTR=20)
    a0.x += pp.x*v4.x; a0.y += pp.x*v4.y; a0.z += pp.x*v4.z; a0.w += pp.x*v4.w;
    a1.x += pp.y*v4.x; a1.y += pp.y*v4.y; a1.z += pp.y*v4.z; a1.w += pp.y*v4.w;
    a2.x += pp.z*v4.x; a2.y += pp.z*v4.y; a2.z += pp.z*v4.z; a2.w += pp.z*v4.w;
    a3.x += pp.w*v4.x; a3.y += pp.w*v4.y; a3.z += pp.w*v4.z; a3.w += pp.w*v4.w;
  }

  h4 o;
  o.x=(_Float16)a0.x; o.y=(_Float16)a0.y; o.z=(_Float16)a0.z; o.w=(_Float16)a0.w;
  *(h4*)&ca[(g4+0)*D_ + d4] = o;
  o.x=(_Float16)a1.x; o.y=(_Float16)a1.y; o.z=(_Float16)a1.z; o.w=(_Float16)a1.w;
  *(h4*)&ca[(g4+1)*D_ + d4] = o;
  o.x=(_Float16)a2.x; o.y=(_Float16)a2.y; o.z=(_Float16)a2.z; o.w=(_Float16)a2.w;
  *(h4*)&ca[(g4+2)*D_ + d4] = o;
  o.x=(_Float16)a3.x; o.y=(_Float16)a3.y; o.z=(_Float16)a3.z; o.w=(_Float16)a3.w;
  *(h4*)&ca[(g4+3)*D_ + d4] = o;
}

__global__ __launch_bounds__(128) void fd_stage2(
    const float* __restrict__ pm_ws, const float* __restrict__ se_ws,
    const _Float16* __restrict__ chunk_acc, float* __restrict__ out)
{
  const int bh  = blockIdx.x;          // b*32 + h
  const int b   = bh >> 5, h = bh & 31;
  const int hkv = h >> 4, g = h & 15;
  const int d   = threadIdx.x;

  float m_r[R_], lse_r[R_];
  #pragma unroll
  for (int r = 0; r < R_; ++r) {
    const int base = ((r*B_ + b)*HKV_ + hkv)*(S_*2);   // widx base; sc = s*2+c
    // pass 1: exact reference m_r = max over S=32 splits of per-split LSE,
    // each split's LSE combined from its two half-chunks
    float m = NEGINF;
    #pragma unroll 8
    for (int s2 = 0; s2 < S_; ++s2) {
      const float pm0 = pm_ws[(base + 2*s2    )*G_ + g];
      const float pm1 = pm_ws[(base + 2*s2 + 1)*G_ + g];
      const float pmx = fmaxf(pm0, pm1);
      if (pmx > NEGINF) {
        const float se0 = se_ws[(base + 2*s2    )*G_ + g];
        const float se1 = se_ws[(base + 2*s2 + 1)*G_ + g];
        const float tt = se0*__expf(pm0 - pmx) + se1*__expf(pm1 - pmx);
        m = fmaxf(m, pmx + __logf(tt));
      }
    }
    // pass 2: exp(lse_r - m) = sum_sc exp(pm_sc - m) * se_sc
    float sum = 0.f;
    #pragma unroll 8
    for (int sc2 = 0; sc2 < S_*2; ++sc2) {
      const float pm = pm_ws[(base + sc2)*G_ + g];
      if (pm > NEGINF) sum += se_ws[(base + sc2)*G_ + g]*__expf(pm - m);
    }
    m_r[r]   = m;
    lse_r[r] = m + __logf(sum);
  }
  const float M = fmaxf(fmaxf(lse_r[0], lse_r[1]), fmaxf(lse_r[2], lse_r[3]));
  float denom = 0.f, o = 0.f;
  #pragma unroll
  for (int r = 0; r < R_; ++r) {
    const float w = __expf(lse_r[r] - M);
    denom += w;
    const int base = ((r*B_ + b)*HKV_ + hkv)*(S_*2);
    float a = 0.f;
    #pragma unroll 4
    for (int sc2 = 0; sc2 < S_*2; ++sc2) {
      const float pm = pm_ws[(base + sc2)*G_ + g];
      if (pm > NEGINF) {                  // block-uniform branch (no d dependence)
        const float wc = __expf(pm - m_r[r]);
        a += wc * (float)chunk_acc[(size_t)(base + sc2)*(G_*D_) + g*D_ + d];
      }
    }
    o += w * a;   // faithful: acc_r UNNORMALIZED, weighted by exp(lse_r - M)
  }
  out[(size_t)bh*D_ + d] = o / denom;
}

extern "C" void kernel_launch(void* const* d_in, const int* in_sizes, int n_in,
                              void* d_out, int out_size, void* d_ws, size_t ws_size,
                              hipStream_t stream) {
  const float* q   = (const float*)d_in[0];
  const float* kc  = (const float*)d_in[1];
  const float* vc  = (const float*)d_in[2];
  const int*   bt  = (const int*)d_in[3];
  const int*   len = (const int*)d_in[4];
  float* out = (float*)d_out;
  float* ws  = (float*)d_ws;

  const size_t nt = (size_t)R_*B_*HKV_*S_*2;       // 8192 tasks
  float*    pm_ws     = ws;                        // [nt][G]
  float*    se_ws     = ws + nt*G_;                // [nt][G]
  _Float16* chunk_acc = (_Float16*)(ws + 2*nt*G_); // [nt][G][D]

  fd_stage1<<<dim3(2*S_*64*HKV_ /* 8192 */), dim3(128), 0, stream>>>(
      q, kc, vc, bt, len, pm_ws, se_ws, chunk_acc);
  fd_stage2<<<dim3(B_*HQ_), dim3(128), 0, stream>>>(
      pm_ws, se_ws, chunk_acc, out);
}

// Round 6
// 305.680 us; speedup vs baseline: 1.5602x; 1.5602x over previous
//
#include <hip/hip_runtime.h>
#include <math.h>

#define R_ 4
#define B_ 16
#define HQ_ 32
#define HKV_ 2
#define G_ 16
#define D_ 128
#define S_ 32     // reference split count (semantically observable via m_r!)
#define CT_ 32    // tokens per sub-chunk task (half-split)
#define L_ 2048
#define P_ 32768
#define KSTR 136  // halves per q_s row: 272B, 16B-aligned rows
#define PSTR 20   // floats per p_s row: 80B stride -> 16B-aligned float4 reads
#define NEGINF (-INFINITY)

typedef _Float16 h4 __attribute__((ext_vector_type(4)));
typedef _Float16 h8 __attribute__((ext_vector_type(8)));
typedef float    fx4 __attribute__((ext_vector_type(4)));

// ws layout (task = (rb,hkv,s,c), widx = ((rb*HKV+hkv)*S + s)*2 + c, 8192 tasks):
//   pm_ws [8192][G] float   (task max score; -inf if empty)
//   se_ws [8192][G] float   (sum exp(s - pm); 0 if empty)
//   chunk_acc [8192][G][D] half  (sum exp(s - pm) * v; ZERO if empty --
//                                 stage2 is branch-free and reads all of it)
//
// Reference semantics note: m_r = max over the S=32 reference splits of the
// per-split LSE (per = ceil(len/32)). This is observable in the output (the
// combine weights acc_r = exp(lse_r - m_r)*o_unnorm by exp(lse_r - M) without
// renormalizing), so stage2 reconstructs lse_s per reference split exactly
// from the two half-split partials. Uniform-chunk m_r (round 4) FAILS.
//
// Stage2 MUST be branch-free (round 5: guarded loads -> VGPR_Count=12 ->
// serialized dependent-load chain -> 217us for 21MB).

__global__ __launch_bounds__(128, 6) void fd_stage1(
    const float* __restrict__ q, const float* __restrict__ kc,
    const float* __restrict__ vc, const int* __restrict__ bt,
    const int* __restrict__ lens,
    float* __restrict__ pm_ws, float* __restrict__ se_ws,
    _Float16* __restrict__ chunk_acc)
{
  const int t   = threadIdx.x;
  const int blk = blockIdx.x;            // grid = 2*S_*64*HKV_ = 8192, c-major
  const int c   = blk >> 12;             // 0 first (large halves), then 1
  const int s   = (blk >> 7) & 31;
  const int rb  = (blk >> 1) & 63;
  const int hkv = blk & 1;
  const int r   = rb >> 4, b = rb & 15;

  const int len = lens[rb];
  const int per = (len + 31) >> 5;       // ceil(len/32), 2..64
  const int sn0 = s*per;                 // reference split start
  const int stn = min(per, len - sn0);   // split token count (may be <=0)
  const int n0  = sn0 + c*CT_;           // sub-chunk start
  const int tn  = min(stn - c*CT_, CT_); // sub-chunk tokens, block-uniform

  const int widx = ((rb*HKV_ + hkv)*S_ + s)*2 + c;
  float* pm_out = pm_ws + widx*G_;
  float* se_out = se_ws + widx*G_;
  _Float16* ca  = chunk_acc + (size_t)widx*(G_*D_);

  if (tn <= 0) {                         // empty task: -inf/0 marker + ZERO acc
    if (t < G_) { pm_out[t] = NEGINF; se_out[t] = 0.f; }
    h8 z = {};
    *(h8*)&ca[t*16]     = z;             // 128 thr x 16 halves = G_*D_
    *(h8*)&ca[t*16 + 8] = z;
    return;
  }

  __shared__ _Float16 q_s[G_][KSTR];                  // 4352 B
  __shared__ __align__(16) float p_s[CT_][PSTR];      // 2560 B
  __shared__ int      pg_s[CT_];                      // 128 B
  __shared__ float2   red_s[2][G_];                   // 256 B  (~7.3 KB total)

  const int* btb = bt + rb*L_;
  const float* kvk = kc + (size_t)r*(P_*HKV_*D_) + hkv*D_;
  const float* kvv = vc + (size_t)r*(P_*HKV_*D_) + hkv*D_;

  // page table slice: n0 <= 31*64 + 32 = 2016, n0+31 <= 2047, always in-bounds
  if (t < CT_) pg_s[t] = btb[n0 + t];

  // stage Q (fp32 -> fp16): 16 heads x 128, coalesced
  {
    const float* qb = q + (b*HQ_ + hkv*G_)*D_;
    int fi = t;
    #pragma unroll
    for (int i = 0; i < 4; ++i, fi += 128) {
      const int g = fi >> 5, dd = (fi & 31)*4;
      const float4 v = *(const float4*)&qb[g*D_ + dd];
      h4 hv; hv.x=(_Float16)v.x; hv.y=(_Float16)v.y; hv.z=(_Float16)v.z; hv.w=(_Float16)v.w;
      *(h4*)&q_s[g][dd] = hv;
    }
  }
  __syncthreads();

  // ---- scores via MFMA, K straight from global.
  // Wave w (0..1) computes D[token 16w..16w+15][head 0..15].
  // A-row = K token row (lane&15), k = 32c + 8*(lane>>4)+j; rows >= tn masked
  // at load (af=0; score later -inf'd). C/D: col(head)=lane&15,
  // row(token_local)=4*(lane>>4)+reg  [verified rounds 1-5].
  const int w  = t >> 6;                  // wave 0..1
  const int l  = t & 63;
  const int hh = l & 15;                  // head / A-row
  const int tq = l >> 4;                  // k-chunk selector
  const bool active = (16*w) < tn;        // wave-uniform

  fx4 d0 = {0.f,0.f,0.f,0.f};
  if (active) {
    const int row = 16*w + hh;
    const bool rowok = row < tn;
    const int pg = pg_s[row];             // valid address even when !rowok
    const float* kr = kvk + pg*(HKV_*D_) + 8*tq;
    #pragma unroll
    for (int cc = 0; cc < 4; ++cc) {      // K = 4 x 32 = 128
      h8 af = {};
      if (rowok) {
        const float4 f0 = *(const float4*)&kr[cc*32];
        const float4 f1 = *(const float4*)&kr[cc*32 + 4];
        af[0]=(_Float16)f0.x; af[1]=(_Float16)f0.y; af[2]=(_Float16)f0.z; af[3]=(_Float16)f0.w;
        af[4]=(_Float16)f1.x; af[5]=(_Float16)f1.y; af[6]=(_Float16)f1.z; af[7]=(_Float16)f1.w;
      }
      const h8 bf = *(const h8*)&q_s[hh][cc*32 + 8*tq];
      d0 = __builtin_amdgcn_mfma_f32_16x16x32_f16(af, bf, d0, 0, 0, 0);
    }
  }

  const float sc = 0.08838834764831845f;  // 128^-0.5
  const int nb = 16*w + 4*tq;             // this lane's token row base
  const float sv0 = (nb+0 < tn) ? d0[0]*sc : NEGINF;
  const float sv1 = (nb+1 < tn) ? d0[1]*sc : NEGINF;
  const float sv2 = (nb+2 < tn) ? d0[2]*sc : NEGINF;
  const float sv3 = (nb+3 < tn) ? d0[3]*sc : NEGINF;

  // wave-local per-head max over this wave's 16 tokens
  float pmw = fmaxf(fmaxf(sv0, sv1), fmaxf(sv2, sv3));
  pmw = fmaxf(pmw, __shfl_xor(pmw, 16));
  pmw = fmaxf(pmw, __shfl_xor(pmw, 32));
  const float pms = (pmw == NEGINF) ? 0.f : pmw;  // avoid (-inf)-(-inf)=NaN
  const float e0 = __expf(sv0 - pms);
  const float e1 = __expf(sv1 - pms);
  const float e2 = __expf(sv2 - pms);
  const float e3 = __expf(sv3 - pms);
  float psw = e0 + e1 + e2 + e3;
  psw += __shfl_xor(psw, 16);
  psw += __shfl_xor(psw, 32);

  if (l < 16) red_s[w][l] = make_float2(pmw, psw);
  __syncthreads();

  // cross-wave combine (2 waves): pm = task max, ps = sum exp(s - pm)
  const float2 r0 = red_s[0][hh], r1 = red_s[1][hh];
  const float pm = fmaxf(r0.x, r1.x);
  const float ps = r0.y*__expf(r0.x - pm) + r1.y*__expf(r1.x - pm);

  if (w == 0 && l < 16) {
    pm_out[l] = pm;                       // task max score
    se_out[l] = ps;                       // task sum exp(s - pm)
  }

  // p transposed: p_s[n][h] = exp(s - pm); rows >= tn of active wave write 0;
  // rows of inactive wave never read (PV loops n < tn)
  if (active) {
    const float cw = __expf(pmw - pm);    // pmw=-inf -> 0
    p_s[nb+0][hh] = e0*cw;
    p_s[nb+1][hh] = e1*cw;
    p_s[nb+2][hh] = e2*cw;
    p_s[nb+3][hh] = e3*cw;
  }
  __syncthreads();

  // PV: thread owns heads g4..g4+3 x dims d4..d4+3; V straight from global,
  // page index from LDS. Wave V-load = 512B contiguous per page row.
  const int d4 = (t & 31)*4;
  const int g4 = (t >> 5)*4;
  const float* vb = kvv + d4;
  float4 a0 = make_float4(0,0,0,0), a1 = make_float4(0,0,0,0);
  float4 a2 = make_float4(0,0,0,0), a3 = make_float4(0,0,0,0);
  #pragma unroll 4
  for (int n = 0; n < tn; ++n) {
    const int pg = pg_s[n];               // LDS broadcast
    const float4 v4 = *(const float4*)&vb[pg*(HKV_*D_)];
    const float4 pp = *(const float4*)&p_s[n][g4];   // 16B-aligned (PSTR=20)
    a0.x += pp.x*v4.x; a0.y += pp.x*v4.y; a0.z += pp.x*v4.z; a0.w += pp.x*v4.w;
    a1.x += pp.y*v4.x; a1.y += pp.y*v4.y; a1.z += pp.y*v4.z; a1.w += pp.y*v4.w;
    a2.x += pp.z*v4.x; a2.y += pp.z*v4.y; a2.z += pp.z*v4.z; a2.w += pp.z*v4.w;
    a3.x += pp.w*v4.x; a3.y += pp.w*v4.y; a3.z += pp.w*v4.z; a3.w += pp.w*v4.w;
  }

  h4 o;
  o.x=(_Float16)a0.x; o.y=(_Float16)a0.y; o.z=(_Float16)a0.z; o.w=(_Float16)a0.w;
  *(h4*)&ca[(g4+0)*D_ + d4] = o;
  o.x=(_Float16)a1.x; o.y=(_Float16)a1.y; o.z=(_Float16)a1.z; o.w=(_Float16)a1.w;
  *(h4*)&ca[(g4+1)*D_ + d4] = o;
  o.x=(_Float16)a2.x; o.y=(_Float16)a2.y; o.z=(_Float16)a2.z; o.w=(_Float16)a2.w;
  *(h4*)&ca[(g4+2)*D_ + d4] = o;
  o.x=(_Float16)a3.x; o.y=(_Float16)a3.y; o.z=(_Float16)a3.z; o.w=(_Float16)a3.w;
  *(h4*)&ca[(g4+3)*D_ + d4] = o;
}

// Branch-free stage2. All loads unguarded (empty tasks have pm=-inf, se=0,
// acc=0: exp(-inf - finite) = 0 annihilates every term; the only -inf - -inf
// hazard is in pass 1's pmx subtraction, handled with a cndmask select).
__global__ __launch_bounds__(128) void fd_stage2(
    const float* __restrict__ pm_ws, const float* __restrict__ se_ws,
    const _Float16* __restrict__ chunk_acc, float* __restrict__ out)
{
  const int bh  = blockIdx.x;          // b*32 + h
  const int b   = bh >> 5, h = bh & 31;
  const int hkv = h >> 4, g = h & 31 & 15;
  const int d   = threadIdx.x;

  float lse_r[R_], a_r[R_];
  #pragma unroll
  for (int r = 0; r < R_; ++r) {
    const int base = ((r*B_ + b)*HKV_ + hkv)*(S_*2);   // widx base; sc = s*2+c
    const float* pmb = pm_ws + base*G_ + g;
    const float* seb = se_ws + base*G_ + g;

    // pass 1: exact reference m_r = max over S=32 splits of per-split LSE,
    // each split's LSE combined from its two half-chunk partials.
    float m = NEGINF;
    #pragma unroll 8
    for (int s2 = 0; s2 < S_; ++s2) {
      const float pm0 = pmb[(2*s2    )*G_];
      const float pm1 = pmb[(2*s2 + 1)*G_];
      const float se0 = seb[(2*s2    )*G_];
      const float se1 = seb[(2*s2 + 1)*G_];
      const float pmx = fmaxf(pm0, pm1);
      const float pmsafe = (pmx == NEGINF) ? 0.f : pmx;   // cndmask, no branch
      const float tt = se0*__expf(pm0 - pmsafe) + se1*__expf(pm1 - pmsafe);
      // empty split: tt=0 -> pmx + log(0) = -inf, absorbed by fmax
      m = fmaxf(m, pmx + __logf(tt));
    }

    // pass 2 (fused): exp(lse_r - m) = sum_sc se*exp(pm - m), and the
    // unnormalized acc_r[d] = sum_sc exp(pm - m) * ca_sc[d]. m finite
    // (len >= 64 guarantees a nonempty split), so empty terms vanish.
    float sum = 0.f, a = 0.f;
    const _Float16* cab = chunk_acc + (size_t)base*(G_*D_) + g*D_ + d;
    #pragma unroll 8
    for (int sc2 = 0; sc2 < S_*2; ++sc2) {
      const float wc = __expf(pmb[sc2*G_] - m);
      sum += seb[sc2*G_] * wc;
      a   += wc * (float)cab[(size_t)sc2*(G_*D_)];
    }
    lse_r[r] = m + __logf(sum);
    a_r[r]   = a;
  }

  const float M = fmaxf(fmaxf(lse_r[0], lse_r[1]), fmaxf(lse_r[2], lse_r[3]));
  float denom = 0.f, o = 0.f;
  #pragma unroll
  for (int r = 0; r < R_; ++r) {
    const float w = __expf(lse_r[r] - M);
    denom += w;
    o += w * a_r[r];   // faithful: acc_r UNNORMALIZED, weighted by exp(lse_r - M)
  }
  out[(size_t)bh*D_ + d] = o / denom;
}

extern "C" void kernel_launch(void* const* d_in, const int* in_sizes, int n_in,
                              void* d_out, int out_size, void* d_ws, size_t ws_size,
                              hipStream_t stream) {
  const float* q   = (const float*)d_in[0];
  const float* kc  = (const float*)d_in[1];
  const float* vc  = (const float*)d_in[2];
  const int*   bt  = (const int*)d_in[3];
  const int*   len = (const int*)d_in[4];
  float* out = (float*)d_out;
  float* ws  = (float*)d_ws;

  const size_t nt = (size_t)R_*B_*HKV_*S_*2;       // 8192 tasks
  float*    pm_ws     = ws;                        // [nt][G]
  float*    se_ws     = ws + nt*G_;                // [nt][G]
  _Float16* chunk_acc = (_Float16*)(ws + 2*nt*G_); // [nt][G][D]

  fd_stage1<<<dim3(2*S_*64*HKV_ /* 8192 */), dim3(128), 0, stream>>>(
      q, kc, vc, bt, len, pm_ws, se_ws, chunk_acc);
  fd_stage2<<<dim3(B_*HQ_), dim3(128), 0, stream>>>(
      pm_ws, se_ws, chunk_acc, out);
}

// Round 7
// 282.628 us; speedup vs baseline: 1.6874x; 1.0816x over previous
//
#include <hip/hip_runtime.h>
#include <math.h>

#define R_ 4
#define B_ 16
#define HQ_ 32
#define HKV_ 2
#define G_ 16
#define D_ 128
#define S_ 32     // reference split count (semantically observable via m_r!)
#define CT_ 32    // tokens per sub-chunk task (half-split)
#define L_ 2048
#define P_ 32768
#define KSTR 136  // halves per q_s row: 272B, 16B-aligned rows
#define PSTR 20   // floats per p_s row: 80B stride -> 16B-aligned float4 reads
#define NEGINF (-INFINITY)

typedef _Float16 h4 __attribute__((ext_vector_type(4)));
typedef _Float16 h8 __attribute__((ext_vector_type(8)));
typedef float    fx4 __attribute__((ext_vector_type(4)));

// ws layout (task = (rb,hkv,c,s), widx = ((rb*HKV+hkv)*2 + c)*S + s, 8192 tasks;
// c-major so stage2 can skip the c=1 block wholesale when len <= 1024):
//   pm_ws [8192][G] float   (task max score; -inf if empty)
//   se_ws [8192][G] float   (sum exp(s - pm); 0 if empty)
//   chunk_acc [8192][G][D] half  (sum exp(s - pm) * v; ZERO if empty)
//
// Reference semantics note: m_r = max over the S=32 reference splits of the
// per-split LSE (per = ceil(len/32)). This is observable in the output (the
// combine weights acc_r = exp(lse_r - m_r)*o_unnorm by exp(lse_r - M) without
// renormalizing), so stage2 reconstructs lse_s per reference split exactly
// from the two half-split partials. Uniform-chunk m_r (round 4) FAILS.
//
// Stage2 must be free of data-dependent load guards (round 5: guarded loads
// -> VGPR_Count=12 -> serialized dependent-load chain -> 217us for 21MB).
// Wave-uniform branches (on len) are fine.
//
// Facts used below (len >= 64, per = ceil(len/32)):
//   two := per > 32  <=>  len > 1024.
//   two  => 31*per < len  (since len > 961), so ALL c=0 halves are non-empty.
//   !two => stn = min(per, len - s*per) <= per <= 32, so ALL c=1 halves empty.

__global__ __launch_bounds__(128, 6) void fd_stage1(
    const float* __restrict__ q, const float* __restrict__ kc,
    const float* __restrict__ vc, const int* __restrict__ bt,
    const int* __restrict__ lens,
    float* __restrict__ pm_ws, float* __restrict__ se_ws,
    _Float16* __restrict__ chunk_acc)
{
  const int t   = threadIdx.x;
  const int blk = blockIdx.x;            // grid = 8192, c-major (LPT: big halves first)
  const int c   = blk >> 12;             // 0 first (large halves), then 1
  const int s   = (blk >> 7) & 31;
  const int rb  = (blk >> 1) & 63;
  const int hkv = blk & 1;
  const int r   = rb >> 4, b = rb & 15;

  const int len = lens[rb];
  const int per = (len + 31) >> 5;       // ceil(len/32), 2..64
  const int sn0 = s*per;                 // reference split start
  const int stn = min(per, len - sn0);   // split token count (may be <=0)
  const int n0  = sn0 + c*CT_;           // sub-chunk start
  const int tn  = min(stn - c*CT_, CT_); // sub-chunk tokens, block-uniform

  const int widx = ((rb*HKV_ + hkv)*2 + c)*S_ + s;   // c-major layout
  float* pm_out = pm_ws + widx*G_;
  float* se_out = se_ws + widx*G_;
  _Float16* ca  = chunk_acc + (size_t)widx*(G_*D_);

  if (tn <= 0) {                         // empty task: -inf/0 marker + ZERO acc
    if (t < G_) { pm_out[t] = NEGINF; se_out[t] = 0.f; }
    h8 z = {};
    *(h8*)&ca[t*16]     = z;             // 128 thr x 16 halves = G_*D_
    *(h8*)&ca[t*16 + 8] = z;
    return;
  }

  __shared__ _Float16 q_s[G_][KSTR];                  // 4352 B
  __shared__ __align__(16) float p_s[CT_][PSTR];      // 2560 B
  __shared__ int      pg_s[CT_];                      // 128 B
  __shared__ float2   red_s[2][G_];                   // 256 B  (~7.3 KB total)

  const int* btb = bt + rb*L_;
  const float* kvk = kc + (size_t)r*(P_*HKV_*D_) + hkv*D_;
  const float* kvv = vc + (size_t)r*(P_*HKV_*D_) + hkv*D_;

  // page table slice: n0 <= 31*64 + 32 = 2016, n0+31 <= 2047, always in-bounds
  if (t < CT_) pg_s[t] = btb[n0 + t];

  // stage Q (fp32 -> fp16): 16 heads x 128, coalesced
  {
    const float* qb = q + (b*HQ_ + hkv*G_)*D_;
    int fi = t;
    #pragma unroll
    for (int i = 0; i < 4; ++i, fi += 128) {
      const int g = fi >> 5, dd = (fi & 31)*4;
      const float4 v = *(const float4*)&qb[g*D_ + dd];
      h4 hv; hv.x=(_Float16)v.x; hv.y=(_Float16)v.y; hv.z=(_Float16)v.z; hv.w=(_Float16)v.w;
      *(h4*)&q_s[g][dd] = hv;
    }
  }
  __syncthreads();

  // ---- scores via MFMA, K straight from global.
  // Wave w (0..1) computes D[token 16w..16w+15][head 0..15].
  // A-row = K token row (lane&15), k = 32cc + 8*(lane>>4)+j; rows >= tn masked
  // at load (af=0; score later -inf'd). C/D: col(head)=lane&15,
  // row(token_local)=4*(lane>>4)+reg  [verified rounds 1-6].
  const int w  = t >> 6;                  // wave 0..1
  const int l  = t & 63;
  const int hh = l & 15;                  // head / A-row
  const int tq = l >> 4;                  // k-chunk selector
  const bool active = (16*w) < tn;        // wave-uniform

  fx4 d0 = {0.f,0.f,0.f,0.f};
  if (active) {
    const int row = 16*w + hh;
    const bool rowok = row < tn;
    const int pg = pg_s[row];             // valid address even when !rowok
    const float* kr = kvk + pg*(HKV_*D_) + 8*tq;
    #pragma unroll
    for (int cc = 0; cc < 4; ++cc) {      // K = 4 x 32 = 128
      h8 af = {};
      if (rowok) {
        const float4 f0 = *(const float4*)&kr[cc*32];
        const float4 f1 = *(const float4*)&kr[cc*32 + 4];
        af[0]=(_Float16)f0.x; af[1]=(_Float16)f0.y; af[2]=(_Float16)f0.z; af[3]=(_Float16)f0.w;
        af[4]=(_Float16)f1.x; af[5]=(_Float16)f1.y; af[6]=(_Float16)f1.z; af[7]=(_Float16)f1.w;
      }
      const h8 bf = *(const h8*)&q_s[hh][cc*32 + 8*tq];
      d0 = __builtin_amdgcn_mfma_f32_16x16x32_f16(af, bf, d0, 0, 0, 0);
    }
  }

  const float sc = 0.08838834764831845f;  // 128^-0.5
  const int nb = 16*w + 4*tq;             // this lane's token row base
  const float sv0 = (nb+0 < tn) ? d0[0]*sc : NEGINF;
  const float sv1 = (nb+1 < tn) ? d0[1]*sc : NEGINF;
  const float sv2 = (nb+2 < tn) ? d0[2]*sc : NEGINF;
  const float sv3 = (nb+3 < tn) ? d0[3]*sc : NEGINF;

  // wave-local per-head max over this wave's 16 tokens
  float pmw = fmaxf(fmaxf(sv0, sv1), fmaxf(sv2, sv3));
  pmw = fmaxf(pmw, __shfl_xor(pmw, 16));
  pmw = fmaxf(pmw, __shfl_xor(pmw, 32));
  const float pms = (pmw == NEGINF) ? 0.f : pmw;  // avoid (-inf)-(-inf)=NaN
  const float e0 = __expf(sv0 - pms);
  const float e1 = __expf(sv1 - pms);
  const float e2 = __expf(sv2 - pms);
  const float e3 = __expf(sv3 - pms);
  float psw = e0 + e1 + e2 + e3;
  psw += __shfl_xor(psw, 16);
  psw += __shfl_xor(psw, 32);

  if (l < 16) red_s[w][l] = make_float2(pmw, psw);
  __syncthreads();

  // cross-wave combine (2 waves): pm = task max, ps = sum exp(s - pm)
  const float2 r0 = red_s[0][hh], r1 = red_s[1][hh];
  const float pm = fmaxf(r0.x, r1.x);
  const float ps = r0.y*__expf(r0.x - pm) + r1.y*__expf(r1.x - pm);

  if (w == 0 && l < 16) {
    pm_out[l] = pm;                       // task max score
    se_out[l] = ps;                       // task sum exp(s - pm)
  }

  // p transposed: p_s[n][h] = exp(s - pm); rows >= tn of active wave write 0;
  // rows of inactive wave never read (PV loops n < tn)
  if (active) {
    const float cw = __expf(pmw - pm);    // pmw=-inf -> 0
    p_s[nb+0][hh] = e0*cw;
    p_s[nb+1][hh] = e1*cw;
    p_s[nb+2][hh] = e2*cw;
    p_s[nb+3][hh] = e3*cw;
  }
  __syncthreads();

  // PV: thread owns heads g4..g4+3 x dims d4..d4+3; V straight from global,
  // page index from LDS. Wave V-load = 512B contiguous per page row.
  const int d4 = (t & 31)*4;
  const int g4 = (t >> 5)*4;
  const float* vb = kvv + d4;
  float4 a0 = make_float4(0,0,0,0), a1 = make_float4(0,0,0,0);
  float4 a2 = make_float4(0,0,0,0), a3 = make_float4(0,0,0,0);
  #pragma unroll 4
  for (int n = 0; n < tn; ++n) {
    const int pg = pg_s[n];               // LDS broadcast
    const float4 v4 = *(const float4*)&vb[pg*(HKV_*D_)];
    const float4 pp = *(const float4*)&p_s[n][g4];   // 16B-aligned (PSTR=20)
    a0.x += pp.x*v4.x; a0.y += pp.x*v4.y; a0.z += pp.x*v4.z; a0.w += pp.x*v4.w;
    a1.x += pp.y*v4.x; a1.y += pp.y*v4.y; a1.z += pp.y*v4.z; a1.w += pp.y*v4.w;
    a2.x += pp.z*v4.x; a2.y += pp.z*v4.y; a2.z += pp.z*v4.z; a2.w += pp.z*v4.w;
    a3.x += pp.w*v4.x; a3.y += pp.w*v4.y; a3.z += pp.w*v4.z; a3.w += pp.w*v4.w;
  }

  h4 o;
  o.x=(_Float16)a0.x; o.y=(_Float16)a0.y; o.z=(_Float16)a0.z; o.w=(_Float16)a0.w;
  *(h4*)&ca[(g4+0)*D_ + d4] = o;
  o.x=(_Float16)a1.x; o.y=(_Float16)a1.y; o.z=(_Float16)a1.z; o.w=(_Float16)a1.w;
  *(h4*)&ca[(g4+1)*D_ + d4] = o;
  o.x=(_Float16)a2.x; o.y=(_Float16)a2.y; o.z=(_Float16)a2.z; o.w=(_Float16)a2.w;
  *(h4*)&ca[(g4+2)*D_ + d4] = o;
  o.x=(_Float16)a3.x; o.y=(_Float16)a3.y; o.z=(_Float16)a3.z; o.w=(_Float16)a3.w;
  *(h4*)&ca[(g4+3)*D_ + d4] = o;
}

// Stage2 v3: 512 threads/block, one 128-thread group per rank (4x shorter
// serial load chain, 8 waves/block -> 16 waves/CU), wave-uniform skip of the
// entire c=1 block when len <= 1024, final cross-rank combine via LDS.
__global__ __launch_bounds__(512) void fd_stage2(
    const float* __restrict__ pm_ws, const float* __restrict__ se_ws,
    const _Float16* __restrict__ chunk_acc, const int* __restrict__ lens,
    float* __restrict__ out)
{
  const int bh  = blockIdx.x;          // b*32 + h
  const int b   = bh >> 5, h = bh & 31;
  const int hkv = h >> 4, g = h & 15;
  const int t   = threadIdx.x;
  const int r   = t >> 7;              // rank group 0..3 (wave-aligned)
  const int d   = t & 127;

  __shared__ float lse_s[R_];
  __shared__ float a_s[R_][D_];

  const int rb  = r*B_ + b;
  const int len = lens[rb];
  const int per = (len + 31) >> 5;
  const bool two = per > 32;           // c=1 halves exist iff len > 1024

  const int cbase = (rb*HKV_ + hkv)*2*S_;     // widx of (c=0, s=0)
  const float* pm0b = pm_ws + cbase*G_ + g;   // stride G_ per s
  const float* se0b = se_ws + cbase*G_ + g;
  const float* pm1b = pm0b + S_*G_;           // c=1 block
  const float* se1b = se0b + S_*G_;

  // pass 1: exact reference m_r = max over S=32 splits of per-split LSE
  float m = NEGINF;
  if (two) {
    // all c=0 halves non-empty (31*per < len) -> pmx finite, no NaN hazard
    #pragma unroll 8
    for (int s = 0; s < S_; ++s) {
      const float pm0 = pm0b[s*G_], pm1 = pm1b[s*G_];
      const float se0 = se0b[s*G_], se1 = se1b[s*G_];
      const float pmx = fmaxf(pm0, pm1);
      const float tt = se0*__expf(pm0 - pmx) + se1*__expf(pm1 - pmx);
      m = fmaxf(m, pmx + __logf(tt));
    }
  } else {
    // split lse = pm0 + log(se0); empty split: -inf + -inf = -inf (no NaN)
    #pragma unroll 8
    for (int s = 0; s < S_; ++s)
      m = fmaxf(m, pm0b[s*G_] + __logf(se0b[s*G_]));
  }

  // pass 2 (fused): exp(lse_r - m) = sum_sc se*exp(pm - m), and the
  // unnormalized acc_r[d] = sum_sc exp(pm - m) * ca[d]. m finite (len >= 64),
  // so empty-chunk terms vanish (pm=-inf -> wc=0; acc zero-filled anyway).
  const int nsc = two ? 2*S_ : S_;     // wave-uniform trip count
  float sum = 0.f, a = 0.f;
  const _Float16* cab = chunk_acc + (size_t)cbase*(G_*D_) + g*D_ + d;
  #pragma unroll 8
  for (int sc2 = 0; sc2 < nsc; ++sc2) {
    const float wc = __expf(pm0b[sc2*G_] - m);
    sum += se0b[sc2*G_] * wc;
    a   += wc * (float)cab[(size_t)sc2*(G_*D_)];
  }

  if (d == 0) lse_s[r] = m + __logf(sum);
  a_s[r][d] = a;
  __syncthreads();

  // cross-rank combine (threads 0..127)
  if (t < D_) {
    const float l0 = lse_s[0], l1 = lse_s[1], l2 = lse_s[2], l3 = lse_s[3];
    const float M  = fmaxf(fmaxf(l0, l1), fmaxf(l2, l3));
    const float w0 = __expf(l0 - M), w1 = __expf(l1 - M);
    const float w2 = __expf(l2 - M), w3 = __expf(l3 - M);
    const float o  = w0*a_s[0][t] + w1*a_s[1][t] + w2*a_s[2][t] + w3*a_s[3][t];
    out[(size_t)bh*D_ + t] = o / (w0 + w1 + w2 + w3);
  }
}

extern "C" void kernel_launch(void* const* d_in, const int* in_sizes, int n_in,
                              void* d_out, int out_size, void* d_ws, size_t ws_size,
                              hipStream_t stream) {
  const float* q   = (const float*)d_in[0];
  const float* kc  = (const float*)d_in[1];
  const float* vc  = (const float*)d_in[2];
  const int*   bt  = (const int*)d_in[3];
  const int*   len = (const int*)d_in[4];
  float* out = (float*)d_out;
  float* ws  = (float*)d_ws;

  const size_t nt = (size_t)R_*B_*HKV_*S_*2;       // 8192 tasks
  float*    pm_ws     = ws;                        // [nt][G]
  float*    se_ws     = ws + nt*G_;                // [nt][G]
  _Float16* chunk_acc = (_Float16*)(ws + 2*nt*G_); // [nt][G][D]

  fd_stage1<<<dim3(8192), dim3(128), 0, stream>>>(
      q, kc, vc, bt, len, pm_ws, se_ws, chunk_acc);
  fd_stage2<<<dim3(B_*HQ_), dim3(512), 0, stream>>>(
      pm_ws, se_ws, chunk_acc, len, out);
}